// Round 1
// baseline (504.726 us; speedup 1.0000x reference)
//
#include <hip/hip_runtime.h>

// Selective-scan (nonlinear Mamba-style) over [B=4, L=4096, DM=1024] fp32.
// s_{t+1} = s_t + softplus(dt_t) * tanh(a_t*s_t + b_t*x_t); y_t = c_t*s_{t+1} + D*x_t
// 4096 independent chains -> 64 waves (1 lane = 1 channel), 64 blocks x 64 threads.
// Memory delivered via global_load_lds (width16): per step one 1KB instr stages
// {x,dt,a,b} (4 streams x 16 lanes x 16B), one 1KB instr per 4 steps stages C.
// 12-chunk (48-step) LDS ring, hand-counted vmcnt, asm ds_reads (avoid compiler
// conservative vmcnt(0) on LDS-DMA aliasing), chunk-ahead register double buffer.

namespace {

constexpr int L_     = 4096;
constexpr int DM_    = 1024;
constexpr int RING   = 12;          // 4-step chunks resident in LDS
constexpr int NCHUNK = L_ / 4;      // 1024

constexpr float LOG2E = 1.4426950408889634f;
constexpr float LN2   = 0.6931471805599453f;
constexpr float KTANH = 2.8853900817779268f;  // 2*log2(e): exp(2z) = exp2(KTANH*z)

typedef float f32x2 __attribute__((ext_vector_type(2)));

__device__ __forceinline__ float fexp2(float x){ float r; asm("v_exp_f32 %0, %1":"=v"(r):"v"(x)); return r; }
__device__ __forceinline__ float flog2(float x){ float r; asm("v_log_f32 %0, %1":"=v"(r):"v"(x)); return r; }
__device__ __forceinline__ float frcp (float x){ float r; asm("v_rcp_f32 %0, %1":"=v"(r):"v"(x)); return r; }

__device__ __forceinline__ unsigned lds_off(void* p){
  return (unsigned)(unsigned long long)(__attribute__((address_space(3))) void*)p;
}

__device__ __forceinline__ void gll16(const float* g, float* l){
  auto g1 = (const __attribute__((address_space(1))) void*)g;
  auto l3 = (__attribute__((address_space(3))) void*)l;
  __builtin_amdgcn_global_load_lds(
      (const __attribute__((address_space(1))) unsigned int*)g1,
      (__attribute__((address_space(3))) unsigned int*)l3,
      16, 0, 0);
}

} // namespace

// ---- per-chunk asm LDS reads into register set (XDn/ABn/Cn), chunk index KC1 ----
#define READN(KC1, XDn, ABn, Cn)                                                         \
  {                                                                                      \
    const int slot_ = (KC1) % RING;                                                      \
    const unsigned am_ = mb_lane + (unsigned)slot_ * 4096u;                              \
    const unsigned ac_ = cb_lane + (unsigned)slot_ * 1024u;                              \
    asm volatile("ds_read2_b32 %0, %1 offset0:0 offset1:64"   : "=v"(XDn[0]) : "v"(am_));          \
    asm volatile("ds_read2_b32 %0, %1 offset0:128 offset1:192": "=v"(ABn[0]) : "v"(am_));          \
    asm volatile("ds_read_b32 %0, %1"                         : "=v"(Cn[0])  : "v"(ac_));          \
    asm volatile("ds_read2_b32 %0, %1 offset0:0 offset1:64"   : "=v"(XDn[1]) : "v"(am_ + 1024u));  \
    asm volatile("ds_read2_b32 %0, %1 offset0:128 offset1:192": "=v"(ABn[1]) : "v"(am_ + 1024u));  \
    asm volatile("ds_read_b32 %0, %1"                         : "=v"(Cn[1])  : "v"(ac_ + 256u));   \
    asm volatile("ds_read2_b32 %0, %1 offset0:0 offset1:64"   : "=v"(XDn[2]) : "v"(am_ + 2048u));  \
    asm volatile("ds_read2_b32 %0, %1 offset0:128 offset1:192": "=v"(ABn[2]) : "v"(am_ + 2048u));  \
    asm volatile("ds_read_b32 %0, %1"                         : "=v"(Cn[2])  : "v"(ac_ + 512u));   \
    asm volatile("ds_read2_b32 %0, %1 offset0:0 offset1:64"   : "=v"(XDn[3]) : "v"(am_ + 3072u));  \
    asm volatile("ds_read2_b32 %0, %1 offset0:128 offset1:192": "=v"(ABn[3]) : "v"(am_ + 3072u));  \
    asm volatile("ds_read_b32 %0, %1"                         : "=v"(Cn[3])  : "v"(ac_ + 768u));   \
  }

// ---- compute 4 steps of chunk KC from current register set ----
#define COMPC(KC, XDc, ABc, Cc)                                                          \
  {                                                                                      \
    _Pragma("unroll")                                                                    \
    for (int j = 0; j < 4; ++j) {                                                        \
      const float xv = XDc[j].x, dtr = XDc[j].y;                                         \
      const float av = ABc[j].x, bv  = ABc[j].y;                                         \
      /* softplus(dtr) = ln2 * log2(1 + 2^(dtr*log2e))  (off critical chain) */          \
      const float e1  = fexp2(dtr * LOG2E);                                              \
      const float dtv = LN2 * flog2(1.0f + e1);                                          \
      /* chain: u=K*(a*s+b*x); e=2^u; th=(e-1)/(e+1); s+=dtv*th */                       \
      const float u = fmaf(av * KTANH, s, (bv * KTANH) * xv);                            \
      float e = fexp2(u);                                                                \
      e = fminf(e, 0x1p60f);        /* inf -> 2^60: th -> 1; underflow 0: th -> -1 */    \
      const float th = (e - 1.0f) * frcp(e + 1.0f);                                      \
      s = fmaf(dtv, th, s);                                                              \
      const float y = fmaf(Cc[j], s, Dv * xv);                                           \
      __builtin_nontemporal_store(y, outp + (size_t)((KC) * 4 + j) * DM_);               \
    }                                                                                    \
  }

// ---- one pipeline phase: wait chunk KC+1 landed, read it, compute KC, prefetch ----
#define PHASE(KC, XDc, ABc, Cc, XDn, ABn, Cn, WVM, DOISSUE)                              \
  {                                                                                      \
    asm volatile("s_waitcnt " WVM ::: "memory");                                         \
    READN((KC) + 1, XDn, ABn, Cn);                                                       \
    COMPC(KC, XDc, ABc, Cc);                                                             \
    if (DOISSUE) issue_chunk((KC) + RING - 1);                                           \
    asm volatile("s_waitcnt lgkmcnt(0)" ::: "memory");                                   \
    __builtin_amdgcn_sched_barrier(0);                                                   \
  }

__global__ __launch_bounds__(64, 1) void ss2d_scan_kernel(
    const float* __restrict__ xs, const float* __restrict__ dts,
    const float* __restrict__ As, const float* __restrict__ Bs,
    const float* __restrict__ Cs, const float* __restrict__ Dp,
    float* __restrict__ out)
{
  // LDS ring: per step 256 floats {x[64],dt[64],a[64],b[64]}; per chunk 4 steps.
  __shared__ float mainBuf[RING * 4 * 256];   // 48 KiB
  __shared__ float cBuf[RING * 256];          // 12 KiB  (C: [chunk][step j][64ch])

  const int lane = threadIdx.x;               // 0..63  == channel within group
  const int blk  = blockIdx.x;                // 0..63
  const int b    = blk >> 4;
  const int dm0  = (blk & 15) << 6;

  const size_t base = ((size_t)b * L_) * DM_ + dm0;

  // load-lane decomposition: q = stream (x,dt,a,b) or step-within-chunk (for C)
  const int q  = lane >> 4;
  const int li = lane & 15;
  const float* sb = (q == 0) ? xs : (q == 1) ? dts : (q == 2) ? As : Bs;
  const float* gmain0 = sb + base + li * 4;                  // + t*DM_ per step
  const float* gc0    = Cs + base + (size_t)q * DM_ + li * 4; // + kc*4*DM_ per chunk

  const float Dv = Dp[dm0 + lane];
  float* outp = out + base + lane;

  const unsigned mb_lane = lds_off(&mainBuf[0]) + (unsigned)lane * 4u;
  const unsigned cb_lane = lds_off(&cBuf[0])    + (unsigned)lane * 4u;

  auto issue_chunk = [&](int kc) {
    const int slot = kc % RING;
    const float* gm = gmain0 + (size_t)(kc * 4) * DM_;
    float* mdst = &mainBuf[slot * 1024];
#pragma unroll
    for (int j = 0; j < 4; ++j)
      gll16(gm + (size_t)j * DM_, mdst + j * 256);   // 1KB: {x,dt,a,b} of step 4kc+j
    gll16(gc0 + (size_t)(kc * 4) * DM_, &cBuf[slot * 256]); // 1KB: C of 4 steps
  };

  float s = 0.0f;

  // prologue: fill RING-1 = 11 chunks (55 load instrs in flight)
  for (int k = 0; k < RING - 1; ++k) issue_chunk(k);
  asm volatile("s_waitcnt vmcnt(50)" ::: "memory");   // chunk 0 complete

  f32x2 xdA[4], abA[4]; float cA[4];
  f32x2 xdB[4], abB[4]; float cB[4];
  READN(0, xdA, abA, cA);
  asm volatile("s_waitcnt lgkmcnt(0)" ::: "memory");
  __builtin_amdgcn_sched_barrier(0);

  int kc = 0;
  // steady state: 55 loads outstanding at wait; vmcnt(45) retires chunks kc,kc+1.
  // Bound: phase kc+1 issues chunk kc+12 -> need kc+12 <= NCHUNK-1 -> kc < NCHUNK-RING.
  for (; kc < NCHUNK - RING; kc += 2) {
    PHASE(kc,     xdA, abA, cA, xdB, abB, cB, "vmcnt(45)", true);
    PHASE(kc + 1, xdB, abB, cB, xdA, abA, cA, "vmcnt(45)", true);
  }
  // tail: no more (or guarded) issues -> full drain is the safe wait
  for (; kc < NCHUNK; kc += 2) {
    PHASE(kc,     xdA, abA, cA, xdB, abB, cB, "vmcnt(0)", (kc + RING - 1 < NCHUNK));
    PHASE(kc + 1, xdB, abB, cB, xdA, abA, cA, "vmcnt(0)", (kc + RING     < NCHUNK));
  }
}

extern "C" void kernel_launch(void* const* d_in, const int* in_sizes, int n_in,
                              void* d_out, int out_size, void* d_ws, size_t ws_size,
                              hipStream_t stream) {
  (void)in_sizes; (void)n_in; (void)out_size; (void)d_ws; (void)ws_size;
  const float* xs  = (const float*)d_in[0];
  const float* dts = (const float*)d_in[1];
  const float* As  = (const float*)d_in[2];
  const float* Bs  = (const float*)d_in[3];
  const float* Cs  = (const float*)d_in[4];
  const float* Dp  = (const float*)d_in[5];
  ss2d_scan_kernel<<<dim3(64), dim3(64), 0, stream>>>(xs, dts, As, Bs, Cs, Dp,
                                                      (float*)d_out);
}

// Round 2
// 382.214 us; speedup vs baseline: 1.3205x; 1.3205x over previous
//
#include <hip/hip_runtime.h>

// Selective scan [B=4, L=4096, DM=1024] fp32:
//   sp = softplus(dt); s' = s + sp*tanh(a*s + b*x); y = c*s' + D*x
// 4096 serial chains. 256 blocks x 64 threads (1 wave), 16 channels/block.
// Chain (lanes, 4x redundant across lane groups of 16):
//   u = fma(Ka, s, Kbx); e = exp2(u); r = rcp(e+1); s' = fma(m2, r, s - 0.5*m2)
//   where Ka = K*a, Kbx = K*b*x, m2 = -2*softplus(dt), K = 2*log2(e).
//   (e=+inf -> r=0 -> s'=s+sp ; e=0 -> r=1 -> s'=s-sp : tanh saturation exact)
// All off-chain work (softplus, products, y-epilogue, coalesced dwordx4 y-store)
// is packed float4 full-wave math interleaved by the scheduler into chain stalls.
// Staging: per chunk (16 steps) 5x global_load_dwordx4 (1KB each) into an
// 8-chunk register ring (40 loads / 40KB in flight), transposed to LDS with
// 3x ds_write_b128. Single wave per block -> no barriers; DS ops are in-order.

namespace {
constexpr int L_     = 4096;
constexpr int DM_    = 1024;
constexpr int CH     = 16;     // channels per block
constexpr int CK     = 16;     // steps per chunk
constexpr int NCHUNK = L_ / CK;        // 256
constexpr int RREG   = 8;              // register-ring depth (chunks)
constexpr size_t CSTRIDE = (size_t)CK * DM_;   // floats per chunk of one stream

constexpr float LOG2E   = 1.4426950408889634f;
constexpr float NEG2LN2 = -1.3862943611198906f;   // -2*ln2
constexpr float KT      = 2.8853900817779268f;    // 2*log2(e)

using f4 = float4;

__device__ __forceinline__ float ex2(float x){ return __builtin_amdgcn_exp2f(x); }
__device__ __forceinline__ float lg2(float x){ return __builtin_amdgcn_logf(x); }
__device__ __forceinline__ float rcpf_(float x){ return __builtin_amdgcn_rcpf(x); }
} // namespace

// ---- stage chunk loads into register-ring slot rs_ (5 x dwordx4 = 5KB/wave) ----
#define LOADC(rs_) {                                                     \
  rx[rs_] = *(const f4*)lgx; lgx += CSTRIDE;                             \
  rd[rs_] = *(const f4*)lgd; lgd += CSTRIDE;                             \
  ra[rs_] = *(const f4*)lga; lga += CSTRIDE;                             \
  rb[rs_] = *(const f4*)lgb; lgb += CSTRIDE;                             \
  rc[rs_] = *(const f4*)lgc; lgc += CSTRIDE;                             \
}

// ---- produce chunk (reg slot rs_) into LDS prod slot ps_: {Kbx, m2, Ka} ----
#define PRODUCE(rs_, ps_) {                                              \
  const f4 x4 = rx[rs_], d4 = rd[rs_], a4 = ra[rs_], b4 = rb[rs_];       \
  cring[ps_] = rc[rs_];                                                  \
  f4 dx4;                                                                \
  dx4.x = D4.x * x4.x; dx4.y = D4.y * x4.y;                              \
  dx4.z = D4.z * x4.z; dx4.w = D4.w * x4.w;                              \
  dxring[ps_] = dx4;                                                     \
  f4 pk4;                                                                \
  pk4.x = (KT * b4.x) * x4.x; pk4.y = (KT * b4.y) * x4.y;                \
  pk4.z = (KT * b4.z) * x4.z; pk4.w = (KT * b4.w) * x4.w;                \
  f4 m24;                                                                \
  m24.x = NEG2LN2 * lg2(1.0f + ex2(LOG2E * d4.x));                       \
  m24.y = NEG2LN2 * lg2(1.0f + ex2(LOG2E * d4.y));                       \
  m24.z = NEG2LN2 * lg2(1.0f + ex2(LOG2E * d4.z));                       \
  m24.w = NEG2LN2 * lg2(1.0f + ex2(LOG2E * d4.w));                       \
  f4 ak4;                                                                \
  ak4.x = KT * a4.x; ak4.y = KT * a4.y;                                  \
  ak4.z = KT * a4.z; ak4.w = KT * a4.w;                                  \
  *(f4*)&prod[ps_][lt][ 0 + 4*lq] = pk4;                                 \
  *(f4*)&prod[ps_][lt][16 + 4*lq] = m24;                                 \
  *(f4*)&prod[ps_][lt][32 + 4*lq] = ak4;                                 \
}

// ---- y-epilogue for a finished chunk: y = c*s' + D*x, coalesced dwordx4 ----
#define YOUT(ss_, cs_) {                                                 \
  const f4 s4 = *(const f4*)&sbuf[ss_][lt][4*lq];                        \
  const f4 c4 = cring[cs_], dx4 = dxring[cs_];                           \
  f4 y4;                                                                 \
  y4.x = fmaf(c4.x, s4.x, dx4.x); y4.y = fmaf(c4.y, s4.y, dx4.y);        \
  y4.z = fmaf(c4.z, s4.z, dx4.z); y4.w = fmaf(c4.w, s4.w, dx4.w);        \
  *(f4*)lgy = y4; lgy += CSTRIDE;                                        \
}

// ---- serial chain: 16 steps of chunk in LDS slot (u_&3); ds reads 2 ahead ----
#define COMPUTE(u_) {                                                    \
  const float* pp = &prod[(u_)&3][0][0];                                 \
  float* sp = &sbuf[(u_)&1][0][0];                                       \
  float pKa = pp[0*48+cc], m2a = pp[0*48+16+cc], ava = pp[0*48+32+cc];   \
  float pKb = pp[1*48+cc], m2b = pp[1*48+16+cc], avb = pp[1*48+32+cc];   \
  _Pragma("unroll")                                                      \
  for (int t = 0; t < CK; ++t) {                                         \
    float pK, m2v, av;                                                   \
    if ((t & 1) == 0) { pK = pKa; m2v = m2a; av = ava; }                 \
    else              { pK = pKb; m2v = m2b; av = avb; }                 \
    const int tp = t + 2;                                                \
    if (tp < CK) {                                                       \
      if ((t & 1) == 0) {                                                \
        pKa = pp[tp*48+cc]; m2a = pp[tp*48+16+cc]; ava = pp[tp*48+32+cc];\
      } else {                                                           \
        pKb = pp[tp*48+cc]; m2b = pp[tp*48+16+cc]; avb = pp[tp*48+32+cc];\
      }                                                                  \
    }                                                                    \
    const float sdt = fmaf(m2v, -0.5f, s);   /* s + softplus(dt)     */  \
    const float uu  = fmaf(av, s, pK);       /* K*(a*s + b*x)        */  \
    const float ee  = ex2(uu);                                           \
    const float rr  = rcpf_(ee + 1.0f);                                  \
    s = fmaf(m2v, rr, sdt);                                              \
    sp[t*64 + lane] = s;                                                 \
  }                                                                      \
}

// ---- one chunk-body of the pipeline ----
#define BODY(u_) {                                                       \
  const int k_ = kb + (u_);                                              \
  if (k_ >= 1)             { YOUT(((u_)+1)&1, ((u_)+3)&3) }              \
  if (k_ + 2 < NCHUNK)     { PRODUCE(((u_)+2)&7, ((u_)+2)&3) }           \
  if (k_ + RREG < NCHUNK)  { LOADC(u_) }                                 \
  COMPUTE(u_);                                                           \
}

__global__ __launch_bounds__(64, 1) void ss2d_scan_kernel(
    const float* __restrict__ xs, const float* __restrict__ dts,
    const float* __restrict__ As, const float* __restrict__ Bs,
    const float* __restrict__ Cs, const float* __restrict__ Dp,
    float* __restrict__ out)
{
  __shared__ float prod[4][CK][48];   // [slot][step][{Kbx[16], m2[16], Ka[16]}]
  __shared__ float sbuf[2][CK][64];   // s' handoff (64-wide absorbs dup lanes)

  const int lane = threadIdx.x;
  // XCD swizzle: hw-bid%8 = XCD; make logical blocks contiguous per XCD so
  // channel-adjacent blocks (sharing 128B lines) hit the same XCD L2.
  const int blk = ((blockIdx.x & 7) << 5) | (blockIdx.x >> 3);   // bijective on 256
  const int b   = blk >> 6;
  const int ch0 = (blk & 63) * CH;

  const size_t base = (size_t)b * L_ * DM_ + ch0;
  const int lt = lane >> 2, lq = lane & 3;          // load mapping: (step, ch-quad)
  const size_t loff = (size_t)lt * DM_ + (size_t)lq * 4;

  const float* lgx = xs  + base + loff;
  const float* lgd = dts + base + loff;
  const float* lga = As  + base + loff;
  const float* lgb = Bs  + base + loff;
  const float* lgc = Cs  + base + loff;
  float*       lgy = out + base + loff;

  const f4 D4 = *(const f4*)(Dp + ch0 + 4 * lq);
  const int cc = lane & 15;                          // compute channel (4x dup)

  f4 rx[RREG], rd[RREG], ra[RREG], rb[RREG], rc[RREG];
  f4 cring[4], dxring[4];

  // prologue: fill register ring (chunks 0..7 -> 40 loads in flight),
  // produce chunks 0,1 into LDS.
  LOADC(0) LOADC(1) LOADC(2) LOADC(3) LOADC(4) LOADC(5) LOADC(6) LOADC(7)
  PRODUCE(0, 0)
  PRODUCE(1, 1)

  float s = 0.0f;

  for (int kb = 0; kb < NCHUNK; kb += RREG) {
    BODY(0) BODY(1) BODY(2) BODY(3) BODY(4) BODY(5) BODY(6) BODY(7)
  }
  // epilogue: y for chunk 255 (s' in sbuf slot 1, c/dx in ring slot 3)
  YOUT(1, 3)
}

extern "C" void kernel_launch(void* const* d_in, const int* in_sizes, int n_in,
                              void* d_out, int out_size, void* d_ws, size_t ws_size,
                              hipStream_t stream) {
  (void)in_sizes; (void)n_in; (void)out_size; (void)d_ws; (void)ws_size;
  const float* xs  = (const float*)d_in[0];
  const float* dts = (const float*)d_in[1];
  const float* As  = (const float*)d_in[2];
  const float* Bs  = (const float*)d_in[3];
  const float* Cs  = (const float*)d_in[4];
  const float* Dp  = (const float*)d_in[5];
  ss2d_scan_kernel<<<dim3(256), dim3(64), 0, stream>>>(xs, dts, As, Bs, Cs, Dp,
                                                       (float*)d_out);
}